// Round 12
// baseline (109.341 us; speedup 1.0000x reference)
//
#include <hip/hip_runtime.h>
#include <hip/hip_bf16.h>

// Problem constants
#define B_DIM   32768
#define A_DIM   64
#define L_DIM   1024          // K
#define N_COLS  128           // 2*A

using bf16x8 = __attribute__((ext_vector_type(8))) __bf16;
using f32x4  = __attribute__((ext_vector_type(4))) float;

// global -> LDS direct (16B per lane; HW: wave-uniform base + lane*16)
#define GLL16(g, l)                                                            \
    __builtin_amdgcn_global_load_lds(                                          \
        (const __attribute__((address_space(1))) unsigned int*)(g),            \
        (__attribute__((address_space(3))) unsigned int*)(l), 16, 0, 0)

// ---------------------------------------------------------------------------
// Pre-kernel: convert W [128 x 1024] f32 -> bf16 in MFMA B-fragment order.
// Unit v (16B): nl=v&15, sub=(v>>4)&3, cf=(v>>6)&7, ks=(v>>9)&31
//   holds Wm[n = cf*16+nl][k = ks*32 + sub*8 + i], i=0..7
// Main kernel: wave w reads breg[ks] = unit ks*512 + w*64 + lane.
// ---------------------------------------------------------------------------
__global__ __launch_bounds__(256)
void convert_w_kernel(const float* __restrict__ W, bf16x8* __restrict__ ws) {
    int v   = blockIdx.x * 256 + threadIdx.x;   // 0..16383
    int nl  = v & 15;
    int sub = (v >> 4) & 3;
    int cf  = (v >> 6) & 7;
    int ks  = (v >> 9) & 31;
    int n   = cf * 16 + nl;
    int k   = ks * 32 + sub * 8;
    const float4* wp = (const float4*)(W + (size_t)n * L_DIM + k);
    float4 w0 = wp[0];
    float4 w1 = wp[1];
    bf16x8 u;
    u[0] = (__bf16)w0.x; u[1] = (__bf16)w0.y;
    u[2] = (__bf16)w0.z; u[3] = (__bf16)w0.w;
    u[4] = (__bf16)w1.x; u[5] = (__bf16)w1.y;
    u[6] = (__bf16)w1.z; u[7] = (__bf16)w1.w;
    ws[v] = u;
}

__device__ __forceinline__ bf16x8 cvt8(float4 a, float4 b) {
    bf16x8 u;
    u[0] = (__bf16)a.x; u[1] = (__bf16)a.y; u[2] = (__bf16)a.z; u[3] = (__bf16)a.w;
    u[4] = (__bf16)b.x; u[5] = (__bf16)b.y; u[6] = (__bf16)b.z; u[7] = (__bf16)b.w;
    return u;
}

// ---------------------------------------------------------------------------
// Main kernel (persistent, row-sequential): grid = 256 = 1 block/CU.
// Block = 512 thr = 8 waves; wave w owns cols [16w,16w+16) x ALL rows; its B
// (16 cols x K=1024, fragment order) lives in breg[32] = 128 VGPR, loaded
// ONCE (acc is only 4 VGPR -> no register pressure, launch_bounds(512,2)).
//
// A: 8 panels of 16 rows x full K = 64 KB CONTIGUOUS global memory each,
// GLL-staged row-major (the CU walks its 512 KB of F sequentially - the
// DRAM-friendly order fillBuffer uses) into a 2 x 64 KB double buffer.
// One barrier per panel; panel p+1 issues before compute(p) and is drained
// by p's end-barrier.
//
// LDS layout, 16B units: u = r*256 + c stores F[row0+r][ (c^(r&7))*4 ..+4 )
// (linear GLL dest + inverse-swizzled global source; read applies the same
// XOR). Read banks spread 8-way -> structural-minimum 8 cy per b128.
// ---------------------------------------------------------------------------
__global__ __launch_bounds__(512, 2)
void branched_policy_kernel(const float* __restrict__ F,
                            const float4* __restrict__ Wf,
                            const float* __restrict__ bias,
                            float* __restrict__ out) {
    __shared__ float4 ldsA[2][4096];   // 2 x 64 KB A panels

    const int tid  = threadIdx.x;
    const int lane = tid & 63;
    const int wave = tid >> 6;        // col-frag 0..7
    const int blk  = blockIdx.x;
    const int lcol = lane & 15;       // fragment row (A) / col (B)
    const int lsub = lane >> 4;       // k subgroup 0..3

    // ---- B: 16 cols x full K -> 128 VGPR, loaded once ----
    bf16x8 breg[32];
    #pragma unroll
    for (int ks = 0; ks < 32; ++ks)
        breg[ks] = *(const bf16x8*)&Wf[ks * 512 + wave * 64 + lane];

    const int   n  = wave * 16 + lcol;
    const float bv = bias[n];
    float* ob = ((n & 1) ? (out + (size_t)B_DIM * A_DIM) : out) + (n >> 1);

    // staging: unit u = i*512 + tid; r = u>>8 (const per wave), c = u&255;
    // source = F[row0 + r][ (c ^ (r&7)) * 4 ]  (permutes 16B chunks within
    // 128B groups -> coalescing preserved)
#define ISSUE_PANEL(P, BUF)                                                    \
    {                                                                          \
        _Pragma("unroll") for (int i = 0; i < 8; ++i) {                        \
            int u = i * 512 + tid;                                             \
            int r = u >> 8;                                                    \
            int c = (u & 255) ^ (r & 7);                                       \
            GLL16(F + (size_t)(blk * 128 + (P) * 16 + r) * L_DIM + c * 4,      \
                  &ldsA[BUF][u]);                                              \
        }                                                                      \
    }

    ISSUE_PANEL(0, 0);
    __syncthreads();                  // panel 0 resident

    #pragma unroll
    for (int p = 0; p < 8; ++p) {
        if (p + 1 < 8) ISSUE_PANEL(p + 1, (p + 1) & 1);   // overlaps compute

        const float4* ab = &ldsA[p & 1][0];
        const int s = lcol & 7;
        f32x4 acc = (f32x4){0.f, 0.f, 0.f, 0.f};
        #pragma unroll
        for (int k = 0; k < 32; ++k) {
            int cbase = k * 8 + lsub * 2;
            float4 a0 = ab[lcol * 256 + ( cbase      ^ s)];
            float4 a1 = ab[lcol * 256 + ((cbase + 1) ^ s)];
            bf16x8 af = cvt8(a0, a1);
            acc = __builtin_amdgcn_mfma_f32_16x16x32_bf16(af, breg[k], acc, 0, 0, 0);
        }

        // ---- epilogue for panel p: bias + tanh + de-interleave ----
        const int rowb = blk * 128 + p * 16 + lsub * 4;
        #pragma unroll
        for (int j = 0; j < 4; ++j) {
            float x = acc[j] + bv;
            float e = __expf(2.0f * x);               // tanh = 1 - 2/(e^2x+1)
            ob[(size_t)(rowb + j) * A_DIM] = 1.0f - 2.0f / (e + 1.0f);
        }

        __syncthreads();   // drains stage(p+1); publishes buffer for reuse
    }
#undef ISSUE_PANEL
}

// ---------------------------------------------------------------------------
// Fallback (v1-style, self-contained) if ws is too small.
// ---------------------------------------------------------------------------
__global__ __launch_bounds__(256, 2)
void fallback_kernel(const float* __restrict__ F,
                     const float* __restrict__ W,
                     const float* __restrict__ bias,
                     float* __restrict__ out) {
    __shared__ bf16x8 ldsB[4096];
    const int tid  = threadIdx.x;
    const int lane = tid & 63;
    const int wave = tid >> 6;
    const int blk  = blockIdx.x;
    const int lcol = lane & 15;
    const int lsub = lane >> 4;
    const int arow = blk * 64 + wave * 16 + lcol;
    const float* Fp = F + (size_t)arow * L_DIM + lsub * 8;

    f32x4 acc[8];
    #pragma unroll
    for (int c = 0; c < 8; ++c) acc[c] = (f32x4){0.f, 0.f, 0.f, 0.f};

    for (int ch = 0; ch < 4; ++ch) {
        __syncthreads();
        #pragma unroll
        for (int i = 0; i < 16; ++i) {
            int v   = i * 256 + tid;
            int nl  = v & 15;
            int sub = (v >> 4) & 3;
            int c   = (v >> 6) & 7;
            int ks  = (v >> 9) & 7;
            int nn  = c * 16 + nl;
            int k   = ch * 256 + ks * 32 + sub * 8;
            const float4* wp = (const float4*)(W + (size_t)nn * L_DIM + k);
            ldsB[v] = cvt8(wp[0], wp[1]);
        }
        __syncthreads();
        #pragma unroll
        for (int ks = 0; ks < 8; ++ks) {
            const float4* ap = (const float4*)(Fp + ch * 256 + ks * 32);
            bf16x8 af = cvt8(ap[0], ap[1]);
            #pragma unroll
            for (int c = 0; c < 8; ++c) {
                bf16x8 bf = ldsB[(ks * 8 + c) * 64 + lane];
                acc[c] = __builtin_amdgcn_mfma_f32_16x16x32_bf16(af, bf, acc[c], 0, 0, 0);
            }
        }
    }

    const int orow0 = blk * 64 + wave * 16 + lsub * 4;
    float* out0 = out;
    float* out1 = out + (size_t)B_DIM * A_DIM;
    #pragma unroll
    for (int c = 0; c < 8; ++c) {
        int   nn  = c * 16 + lcol;
        float bvv = bias[nn];
        float* obp = (nn & 1) ? out1 : out0;
        #pragma unroll
        for (int j = 0; j < 4; ++j) {
            float x = acc[c][j] + bvv;
            float e = __expf(2.0f * x);
            obp[(size_t)(orow0 + j) * A_DIM + (nn >> 1)] = 1.0f - 2.0f / (e + 1.0f);
        }
    }
}

extern "C" void kernel_launch(void* const* d_in, const int* in_sizes, int n_in,
                              void* d_out, int out_size, void* d_ws, size_t ws_size,
                              hipStream_t stream) {
    const float* F    = (const float*)d_in[0];  // [32768, 1024] f32
    const float* W    = (const float*)d_in[1];  // [64, 2, 1024] f32
    const float* bias = (const float*)d_in[2];  // [64, 2] f32
    float* outp       = (float*)d_out;          // [2][32768, 64] f32

    const size_t ws_needed = (size_t)N_COLS * L_DIM * sizeof(__bf16);  // 256 KB

    if (ws_size >= ws_needed) {
        bf16x8* wf = (bf16x8*)d_ws;
        hipLaunchKernelGGL(convert_w_kernel, dim3(64), dim3(256), 0, stream, W, wf);
        hipLaunchKernelGGL(branched_policy_kernel, dim3(B_DIM / 128), dim3(512), 0, stream,
                           F, (const float4*)wf, bias, outp);
    } else {
        hipLaunchKernelGGL(fallback_kernel, dim3(B_DIM / 64), dim3(256), 0, stream,
                           F, W, bias, outp);
    }
}